// Round 2
// baseline (1207.702 us; speedup 1.0000x reference)
//
#include <hip/hip_runtime.h>
#include <hip/hip_bf16.h>
#include <cstdint>
#include <cstddef>

#define D_DIM 2048
#define L_SEQ 4096
#define N_BATCH 4
#define M_ROWS (L_SEQ * N_BATCH)   // 16384
#define NCHUNK 64
#define LCHUNK (L_SEQ / NCHUNK)    // 64

typedef __bf16 bf16_t;
typedef __bf16 bf16x4_t __attribute__((ext_vector_type(4)));
typedef __bf16 bf16x8_t __attribute__((ext_vector_type(8)));
typedef float f32x4_t __attribute__((ext_vector_type(4)));

// ---------------- fp32 -> bf16 convert (vectorized) ----------------
__global__ __launch_bounds__(256) void cvt_f32_to_bf16(const float* __restrict__ in,
                                                       bf16_t* __restrict__ out, int n4) {
  int idx = blockIdx.x * blockDim.x + threadIdx.x;
  int stride = gridDim.x * blockDim.x;
  const float4* in4 = reinterpret_cast<const float4*>(in);
  bf16x4_t* out4 = reinterpret_cast<bf16x4_t*>(out);
  for (int i = idx; i < n4; i += stride) {
    float4 v = in4[i];
    bf16x4_t o;
    o[0] = (bf16_t)v.x; o[1] = (bf16_t)v.y; o[2] = (bf16_t)v.z; o[3] = (bf16_t)v.w;
    out4[i] = o;
  }
}

// ------- bf16 GEMM: C[M][N] = A[M][K] * Wt[N][K]^T (OutT = float or bf16) -------
#define BM 128
#define BN 128
#define BK 32

template <typename OutT>
__global__ __launch_bounds__(256) void gemm_bt(const bf16_t* __restrict__ A,
                                               const bf16_t* __restrict__ Wt,
                                               OutT* __restrict__ C,
                                               int M, int N, int K) {
  __shared__ bf16_t As[BM][BK];
  __shared__ bf16_t Bs[BN][BK];
  const int tid = threadIdx.x;
  const int wave = tid >> 6;
  const int lane = tid & 63;
  const int m0 = blockIdx.y * BM;
  const int n0 = blockIdx.x * BN;
  const int wm = (wave >> 1) * 64;   // 2x2 waves, each 64x64
  const int wn = (wave & 1) * 64;
  const int fr = lane & 15;          // fragment row/col
  const int fk = (lane >> 4) * 8;    // fragment k offset (contiguous 8)

  f32x4_t acc[4][4] = {};

  const int Kv = K >> 3;  // row stride in uint4 (8 bf16) units
  const uint4* Ag = reinterpret_cast<const uint4*>(A) + (size_t)m0 * Kv;
  const uint4* Bg = reinterpret_cast<const uint4*>(Wt) + (size_t)n0 * Kv;
  uint4* Asv = reinterpret_cast<uint4*>(&As[0][0]);
  uint4* Bsv = reinterpret_cast<uint4*>(&Bs[0][0]);

  for (int kt = 0; kt < K; kt += BK) {
    const int kv0 = kt >> 3;
    #pragma unroll
    for (int s = 0; s < 2; ++s) {
      int idx = tid + s * 256;      // 512 uint4 per 128x32 tile
      int r = idx >> 2, c = idx & 3;
      Asv[idx] = Ag[(size_t)r * Kv + kv0 + c];
      Bsv[idx] = Bg[(size_t)r * Kv + kv0 + c];
    }
    __syncthreads();
    bf16x8_t af[4], bfv[4];
    #pragma unroll
    for (int mi = 0; mi < 4; ++mi)
      af[mi] = *reinterpret_cast<const bf16x8_t*>(&As[wm + mi * 16 + fr][fk]);
    #pragma unroll
    for (int ni = 0; ni < 4; ++ni)
      bfv[ni] = *reinterpret_cast<const bf16x8_t*>(&Bs[wn + ni * 16 + fr][fk]);
    #pragma unroll
    for (int mi = 0; mi < 4; ++mi) {
      #pragma unroll
      for (int ni = 0; ni < 4; ++ni)
        acc[mi][ni] = __builtin_amdgcn_mfma_f32_16x16x32_bf16(af[mi], bfv[ni], acc[mi][ni], 0, 0, 0);
    }
    __syncthreads();
  }

  // C/D layout: col = lane&15, row = 4*(lane>>4) + reg   [m89-verified]
  const int crow = (lane >> 4) * 4;
  const int ccol = lane & 15;
  #pragma unroll
  for (int mi = 0; mi < 4; ++mi) {
    #pragma unroll
    for (int r = 0; r < 4; ++r) {
      int gm = m0 + wm + mi * 16 + crow + r;
      OutT* Cp = C + (size_t)gm * N + n0 + wn + ccol;
      #pragma unroll
      for (int ni = 0; ni < 4; ++ni)
        Cp[ni * 16] = (OutT)acc[mi][ni][r];
    }
  }
}

// ---------------- chunked scan: h_t = gate_t * h_{t-1} + iin_t ----------------
__device__ __forceinline__ float sigmoidf_fast(float x) {
  return 1.0f / (1.0f + __expf(-x));
}

__global__ __launch_bounds__(256) void scan_phaseA(const bf16_t* __restrict__ f,
                                                   const bf16_t* __restrict__ i_,
                                                   float* __restrict__ cA,
                                                   float* __restrict__ cB) {
  const int d = blockIdx.x * 256 + threadIdx.x;   // grid.x = D/256
  const int c = blockIdx.y;                       // chunk
  const int b = blockIdx.z;                       // batch
  size_t base = ((size_t)b * L_SEQ + (size_t)c * LCHUNK) * D_DIM + d;
  float aprod = 1.0f, h = 0.0f;
  for (int t = 0; t < LCHUNK; ++t) {
    float fv = (float)f[base + (size_t)t * D_DIM];
    float iv = (float)i_[base + (size_t)t * D_DIM];
    float gate = sigmoidf_fast(fv);
    float iin = iv * sigmoidf_fast(iv) * (1.0f - gate);
    aprod *= gate;
    h = gate * h + iin;
  }
  size_t p = ((size_t)b * NCHUNK + c) * D_DIM + d;
  cA[p] = aprod;
  cB[p] = h;
}

__global__ __launch_bounds__(256) void scan_phaseB(const float* __restrict__ cA,
                                                   const float* __restrict__ cB,
                                                   float* __restrict__ hin) {
  int idx = blockIdx.x * blockDim.x + threadIdx.x;  // over B*D = 8192
  int b = idx >> 11;
  int d = idx & (D_DIM - 1);
  float h = 0.0f;
  for (int c = 0; c < NCHUNK; ++c) {
    size_t p = ((size_t)b * NCHUNK + c) * D_DIM + d;
    hin[p] = h;
    h = cA[p] * h + cB[p];
  }
}

__global__ __launch_bounds__(256) void scan_phaseC(const bf16_t* __restrict__ f,
                                                   const bf16_t* __restrict__ i_,
                                                   const float* __restrict__ hin,
                                                   bf16_t* __restrict__ o) {
  const int d = blockIdx.x * 256 + threadIdx.x;
  const int c = blockIdx.y;
  const int b = blockIdx.z;
  size_t base = ((size_t)b * L_SEQ + (size_t)c * LCHUNK) * D_DIM + d;
  float h = hin[((size_t)b * NCHUNK + c) * D_DIM + d];
  for (int t = 0; t < LCHUNK; ++t) {
    float fv = (float)f[base + (size_t)t * D_DIM];
    float iv = (float)i_[base + (size_t)t * D_DIM];  // NOTE: o aliases i_ — read before write
    float gate = sigmoidf_fast(fv);
    float iin = iv * sigmoidf_fast(iv) * (1.0f - gate);
    h = gate * h + iin;
    o[base + (size_t)t * D_DIM] = (bf16_t)h;
  }
}

// ---------------- RMSNorm(g)*w * swish(o) -> bf16 (inner may alias o) ----------------
__global__ __launch_bounds__(256) void norm_gate(const bf16_t* __restrict__ g,
                                                 const bf16_t* __restrict__ o,
                                                 const float* __restrict__ w,
                                                 bf16_t* __restrict__ inner) {
  const int row = blockIdx.x;
  const int tid = threadIdx.x;   // 256 threads, 8 elems each
  const bf16x8_t* g8 = reinterpret_cast<const bf16x8_t*>(g + (size_t)row * D_DIM);
  const bf16x8_t* o8 = reinterpret_cast<const bf16x8_t*>(o + (size_t)row * D_DIM);
  const float4* w4 = reinterpret_cast<const float4*>(w);
  bf16x8_t gv = g8[tid];
  float gf[8];
  float ss = 0.0f;
  #pragma unroll
  for (int j = 0; j < 8; ++j) { gf[j] = (float)gv[j]; ss += gf[j] * gf[j]; }
  #pragma unroll
  for (int off = 32; off > 0; off >>= 1) ss += __shfl_down(ss, off, 64);
  __shared__ float red[4];
  if ((tid & 63) == 0) red[tid >> 6] = ss;
  __syncthreads();
  float tot = red[0] + red[1] + red[2] + red[3];
  float rms = rsqrtf(tot * (1.0f / D_DIM) + 1e-5f);

  bf16x8_t ov = o8[tid];               // read BEFORE writing inner (may alias)
  float4 wa = w4[tid * 2], wb = w4[tid * 2 + 1];
  float wf[8] = {wa.x, wa.y, wa.z, wa.w, wb.x, wb.y, wb.z, wb.w};
  bf16x8_t r;
  #pragma unroll
  for (int j = 0; j < 8; ++j) {
    float of = (float)ov[j];
    r[j] = (bf16_t)(gf[j] * rms * wf[j] * (of * sigmoidf_fast(of)));
  }
  bf16x8_t* inn8 = reinterpret_cast<bf16x8_t*>(inner + (size_t)row * D_DIM);
  inn8[tid] = r;
}

// ---------------- launch ----------------
extern "C" void kernel_launch(void* const* d_in, const int* in_sizes, int n_in,
                              void* d_out, int out_size, void* d_ws, size_t ws_size,
                              hipStream_t stream) {
  const float* x  = (const float*)d_in[0];
  const float* Wi = (const float*)d_in[1];
  const float* Wf = (const float*)d_in[2];
  const float* Wg = (const float*)d_in[3];
  const float* w  = (const float*)d_in[4];
  const float* Wo = (const float*)d_in[5];
  float* out = (float*)d_out;

  const size_t MD = (size_t)M_ROWS * D_DIM;   // 33.5M elems
  const size_t DD = (size_t)D_DIM * D_DIM;    // 4.2M elems
  const size_t MiB = 1024 * 1024;

  // d_out (128 MiB) doubles as staging for bf16 x and Wi/Wf/Wg.
  // All of it is dead before the final GEMM writes d_out (stream-ordered).
  char* ob = (char*)d_out;
  bf16_t* xb  = (bf16_t*)(ob);             // 64 MiB
  bf16_t* wib = (bf16_t*)(ob + 64 * MiB);  // 8 MiB
  bf16_t* wfb = (bf16_t*)(ob + 72 * MiB);  // 8 MiB
  bf16_t* wgb = (bf16_t*)(ob + 80 * MiB);  // 8 MiB  (total 88 <= 128 MiB)

  // workspace: 142 MiB total
  char* ws = (char*)d_ws;
  bf16_t* B0  = (bf16_t*)(ws);             // 64 MiB: i -> o -> inner
  bf16_t* B1  = (bf16_t*)(ws + 64 * MiB);  // 64 MiB: f -> g
  bf16_t* wob = (bf16_t*)(ws + 128 * MiB); // 8 MiB  (ws, NOT d_out: final GEMM reads it)
  float*  cA  = (float*)(ws + 136 * MiB);  // 2 MiB
  float*  cB  = (float*)(ws + 138 * MiB);  // 2 MiB
  float*  hin = (float*)(ws + 140 * MiB);  // 2 MiB

  // 1. convert inputs to bf16
  cvt_f32_to_bf16<<<2048, 256, 0, stream>>>(x, xb, (int)(MD / 4));
  cvt_f32_to_bf16<<<512, 256, 0, stream>>>(Wi, wib, (int)(DD / 4));
  cvt_f32_to_bf16<<<512, 256, 0, stream>>>(Wf, wfb, (int)(DD / 4));
  cvt_f32_to_bf16<<<512, 256, 0, stream>>>(Wg, wgb, (int)(DD / 4));
  cvt_f32_to_bf16<<<512, 256, 0, stream>>>(Wo, wob, (int)(DD / 4));

  // 2. i/f projections -> bf16
  dim3 ggrid(D_DIM / BN, M_ROWS / BM);
  gemm_bt<bf16_t><<<ggrid, 256, 0, stream>>>(xb, wib, B0, M_ROWS, D_DIM, D_DIM);
  gemm_bt<bf16_t><<<ggrid, 256, 0, stream>>>(xb, wfb, B1, M_ROWS, D_DIM, D_DIM);

  // 3. chunked scan (o written in-place over i in B0)
  dim3 sgrid(D_DIM / 256, NCHUNK, N_BATCH);
  scan_phaseA<<<sgrid, 256, 0, stream>>>(B1, B0, cA, cB);
  scan_phaseB<<<32, 256, 0, stream>>>(cA, cB, hin);
  scan_phaseC<<<sgrid, 256, 0, stream>>>(B1, B0, hin, B0);

  // 4. g projection -> bf16 (overwrites f in B1; f consumed by phaseC)
  gemm_bt<bf16_t><<<ggrid, 256, 0, stream>>>(xb, wgb, B1, M_ROWS, D_DIM, D_DIM);

  // 5. rmsnorm + swish gate -> bf16 inner (in-place over o in B0)
  norm_gate<<<M_ROWS, 256, 0, stream>>>(B1, B0, w, B0);

  // 6. output projection -> fp32 d_out (xb/weights in d_out now dead)
  gemm_bt<float><<<ggrid, 256, 0, stream>>>(B0, wob, out, M_ROWS, D_DIM, D_DIM);
}

// Round 3
// 1134.915 us; speedup vs baseline: 1.0641x; 1.0641x over previous
//
#include <hip/hip_runtime.h>
#include <hip/hip_bf16.h>
#include <cstdint>
#include <cstddef>

#define D_DIM 2048
#define L_SEQ 4096
#define N_BATCH 4
#define M_ROWS (L_SEQ * N_BATCH)   // 16384
#define NCHUNK 64
#define LCHUNK (L_SEQ / NCHUNK)    // 64

typedef __bf16 bf16_t;
typedef __bf16 bf16x4_t __attribute__((ext_vector_type(4)));
typedef __bf16 bf16x8_t __attribute__((ext_vector_type(8)));
typedef float f32x4_t __attribute__((ext_vector_type(4)));

// ---------------- async global->LDS, 16B per lane ----------------
__device__ __forceinline__ void gload_lds16(const void* g, void* l) {
  __builtin_amdgcn_global_load_lds(
      (const __attribute__((address_space(1))) void*)g,
      (__attribute__((address_space(3))) void*)l, 16, 0, 0);
}

// ---------------- fp32 -> bf16 convert (vectorized) ----------------
__global__ __launch_bounds__(256) void cvt_f32_to_bf16(const float* __restrict__ in,
                                                       bf16_t* __restrict__ out, int n4) {
  int idx = blockIdx.x * blockDim.x + threadIdx.x;
  int stride = gridDim.x * blockDim.x;
  const float4* in4 = reinterpret_cast<const float4*>(in);
  bf16x4_t* out4 = reinterpret_cast<bf16x4_t*>(out);
  for (int i = idx; i < n4; i += stride) {
    float4 v = in4[i];
    bf16x4_t o;
    o[0] = (bf16_t)v.x; o[1] = (bf16_t)v.y; o[2] = (bf16_t)v.z; o[3] = (bf16_t)v.w;
    out4[i] = o;
  }
}

// 4 weight matrices in one dispatch (blockIdx.y selects)
struct CvtBatch { const float* src[4]; bf16_t* dst[4]; };
__global__ __launch_bounds__(256) void cvt4_f32_to_bf16(CvtBatch cb, int n4) {
  const float4* in4 = reinterpret_cast<const float4*>(cb.src[blockIdx.y]);
  bf16x4_t* out4 = reinterpret_cast<bf16x4_t*>(cb.dst[blockIdx.y]);
  int stride = gridDim.x * blockDim.x;
  for (int i = blockIdx.x * blockDim.x + threadIdx.x; i < n4; i += stride) {
    float4 v = in4[i];
    bf16x4_t o;
    o[0] = (bf16_t)v.x; o[1] = (bf16_t)v.y; o[2] = (bf16_t)v.z; o[3] = (bf16_t)v.w;
    out4[i] = o;
  }
}

// ------- bf16 GEMM: C[M][N] = A[M][K] * Wt[N][K]^T (OutT = float or bf16) -------
// m97 structure: 128x128 tile, BK=32, global_load_lds(16B) staging, XCD swizzle.
#define BM 128
#define BN 128
#define BK 32

template <typename OutT>
__global__ __launch_bounds__(256) void gemm_bt(const bf16_t* __restrict__ A,
                                               const bf16_t* __restrict__ Wt,
                                               OutT* __restrict__ C,
                                               int M, int N, int K) {
  __shared__ bf16_t As[BM][BK];   // 8 KiB, linear in lane order for global_load_lds
  __shared__ bf16_t Bs[BN][BK];   // 8 KiB
  const int tid = threadIdx.x;
  const int wave = tid >> 6;
  const int lane = tid & 63;

  // XCD-aware swizzle: nwg = 16*128 = 2048, divisible by 8 -> simple variant bijective.
  const int nbx = gridDim.x;
  const int nwg = nbx * gridDim.y;
  const int bid = blockIdx.y * nbx + blockIdx.x;
  const int cpx = nwg >> 3;
  const int swz = (bid & 7) * cpx + (bid >> 3);
  const int by = swz / nbx;       // consecutive swz share by (A panel), bx varies
  const int bx = swz - by * nbx;

  const int m0 = by * BM;
  const int n0 = bx * BN;
  const int wm = (wave >> 1) * 64;   // 2x2 waves, each 64x64
  const int wn = (wave & 1) * 64;
  const int fr = lane & 15;          // fragment row/col
  const int fk = (lane >> 4) * 8;    // fragment k offset (contiguous 8)

  f32x4_t acc[4][4] = {};

  const int Kv = K >> 3;  // row stride in uint4 (8 bf16) units
  const uint4* Ag = reinterpret_cast<const uint4*>(A) + (size_t)m0 * Kv;
  const uint4* Bg = reinterpret_cast<const uint4*>(Wt) + (size_t)n0 * Kv;
  uint4* Asv = reinterpret_cast<uint4*>(&As[0][0]);
  uint4* Bsv = reinterpret_cast<uint4*>(&Bs[0][0]);

  // staging indices: thread covers chunks idx, idx+256 (512 uint4 per 128x32 tile)
  const int r0 = tid >> 2, c0 = tid & 3;           // idx = tid
  const int r1 = (tid + 256) >> 2, c1 = tid & 3;   // idx+256: low 2 bits unchanged

  for (int kt = 0; kt < K; kt += BK) {
    const int kv0 = kt >> 3;
    gload_lds16(Ag + (size_t)r0 * Kv + kv0 + c0, Asv + tid);
    gload_lds16(Ag + (size_t)r1 * Kv + kv0 + c1, Asv + tid + 256);
    gload_lds16(Bg + (size_t)r0 * Kv + kv0 + c0, Bsv + tid);
    gload_lds16(Bg + (size_t)r1 * Kv + kv0 + c1, Bsv + tid + 256);
    __syncthreads();   // drains vmcnt (compiler emits s_waitcnt vmcnt(0) before s_barrier)
    bf16x8_t af[4], bfv[4];
    #pragma unroll
    for (int mi = 0; mi < 4; ++mi)
      af[mi] = *reinterpret_cast<const bf16x8_t*>(&As[wm + mi * 16 + fr][fk]);
    #pragma unroll
    for (int ni = 0; ni < 4; ++ni)
      bfv[ni] = *reinterpret_cast<const bf16x8_t*>(&Bs[wn + ni * 16 + fr][fk]);
    #pragma unroll
    for (int mi = 0; mi < 4; ++mi) {
      #pragma unroll
      for (int ni = 0; ni < 4; ++ni)
        acc[mi][ni] = __builtin_amdgcn_mfma_f32_16x16x32_bf16(af[mi], bfv[ni], acc[mi][ni], 0, 0, 0);
    }
    __syncthreads();
  }

  // C/D layout: col = lane&15, row = 4*(lane>>4) + reg   [m89-verified]
  const int crow = (lane >> 4) * 4;
  const int ccol = lane & 15;
  #pragma unroll
  for (int mi = 0; mi < 4; ++mi) {
    #pragma unroll
    for (int r = 0; r < 4; ++r) {
      int gm = m0 + wm + mi * 16 + crow + r;
      OutT* Cp = C + (size_t)gm * N + n0 + wn + ccol;
      #pragma unroll
      for (int ni = 0; ni < 4; ++ni)
        Cp[ni * 16] = (OutT)acc[mi][ni][r];
    }
  }
}

// ---------------- chunked scan: h_t = gate_t * h_{t-1} + iin_t ----------------
__device__ __forceinline__ float sigmoidf_fast(float x) {
  return 1.0f / (1.0f + __expf(-x));
}

__global__ __launch_bounds__(256) void scan_phaseA(const bf16_t* __restrict__ f,
                                                   const bf16_t* __restrict__ i_,
                                                   float* __restrict__ cA,
                                                   float* __restrict__ cB) {
  const int d = blockIdx.x * 256 + threadIdx.x;   // grid.x = D/256
  const int c = blockIdx.y;                       // chunk
  const int b = blockIdx.z;                       // batch
  size_t base = ((size_t)b * L_SEQ + (size_t)c * LCHUNK) * D_DIM + d;
  float aprod = 1.0f, h = 0.0f;
  for (int t = 0; t < LCHUNK; ++t) {
    float fv = (float)f[base + (size_t)t * D_DIM];
    float iv = (float)i_[base + (size_t)t * D_DIM];
    float gate = sigmoidf_fast(fv);
    float iin = iv * sigmoidf_fast(iv) * (1.0f - gate);
    aprod *= gate;
    h = gate * h + iin;
  }
  size_t p = ((size_t)b * NCHUNK + c) * D_DIM + d;
  cA[p] = aprod;
  cB[p] = h;
}

__global__ __launch_bounds__(256) void scan_phaseB(const float* __restrict__ cA,
                                                   const float* __restrict__ cB,
                                                   float* __restrict__ hin) {
  int idx = blockIdx.x * blockDim.x + threadIdx.x;  // over B*D = 8192
  int b = idx >> 11;
  int d = idx & (D_DIM - 1);
  float h = 0.0f;
  for (int c = 0; c < NCHUNK; ++c) {
    size_t p = ((size_t)b * NCHUNK + c) * D_DIM + d;
    hin[p] = h;
    h = cA[p] * h + cB[p];
  }
}

__global__ __launch_bounds__(256) void scan_phaseC(const bf16_t* __restrict__ f,
                                                   const bf16_t* __restrict__ i_,
                                                   const float* __restrict__ hin,
                                                   bf16_t* __restrict__ o) {
  const int d = blockIdx.x * 256 + threadIdx.x;
  const int c = blockIdx.y;
  const int b = blockIdx.z;
  size_t base = ((size_t)b * L_SEQ + (size_t)c * LCHUNK) * D_DIM + d;
  float h = hin[((size_t)b * NCHUNK + c) * D_DIM + d];
  for (int t = 0; t < LCHUNK; ++t) {
    float fv = (float)f[base + (size_t)t * D_DIM];
    float iv = (float)i_[base + (size_t)t * D_DIM];  // o aliases i_ — read before write
    float gate = sigmoidf_fast(fv);
    float iin = iv * sigmoidf_fast(iv) * (1.0f - gate);
    h = gate * h + iin;
    o[base + (size_t)t * D_DIM] = (bf16_t)h;
  }
}

// ---------------- RMSNorm(g)*w * swish(o) -> bf16 (inner may alias o) ----------------
__global__ __launch_bounds__(256) void norm_gate(const bf16_t* __restrict__ g,
                                                 const bf16_t* __restrict__ o,
                                                 const float* __restrict__ w,
                                                 bf16_t* __restrict__ inner) {
  const int row = blockIdx.x;
  const int tid = threadIdx.x;   // 256 threads, 8 elems each
  const bf16x8_t* g8 = reinterpret_cast<const bf16x8_t*>(g + (size_t)row * D_DIM);
  const bf16x8_t* o8 = reinterpret_cast<const bf16x8_t*>(o + (size_t)row * D_DIM);
  const float4* w4 = reinterpret_cast<const float4*>(w);
  bf16x8_t gv = g8[tid];
  float gf[8];
  float ss = 0.0f;
  #pragma unroll
  for (int j = 0; j < 8; ++j) { gf[j] = (float)gv[j]; ss += gf[j] * gf[j]; }
  #pragma unroll
  for (int off = 32; off > 0; off >>= 1) ss += __shfl_down(ss, off, 64);
  __shared__ float red[4];
  if ((tid & 63) == 0) red[tid >> 6] = ss;
  __syncthreads();
  float tot = red[0] + red[1] + red[2] + red[3];
  float rms = rsqrtf(tot * (1.0f / D_DIM) + 1e-5f);

  bf16x8_t ov = o8[tid];               // read BEFORE writing inner (may alias)
  float4 wa = w4[tid * 2], wb = w4[tid * 2 + 1];
  float wf[8] = {wa.x, wa.y, wa.z, wa.w, wb.x, wb.y, wb.z, wb.w};
  bf16x8_t r;
  #pragma unroll
  for (int j = 0; j < 8; ++j) {
    float of = (float)ov[j];
    r[j] = (bf16_t)(gf[j] * rms * wf[j] * (of * sigmoidf_fast(of)));
  }
  bf16x8_t* inn8 = reinterpret_cast<bf16x8_t*>(inner + (size_t)row * D_DIM);
  inn8[tid] = r;
}

// ---------------- launch ----------------
extern "C" void kernel_launch(void* const* d_in, const int* in_sizes, int n_in,
                              void* d_out, int out_size, void* d_ws, size_t ws_size,
                              hipStream_t stream) {
  const float* x  = (const float*)d_in[0];
  const float* Wi = (const float*)d_in[1];
  const float* Wf = (const float*)d_in[2];
  const float* Wg = (const float*)d_in[3];
  const float* w  = (const float*)d_in[4];
  const float* Wo = (const float*)d_in[5];
  float* out = (float*)d_out;

  const size_t MD = (size_t)M_ROWS * D_DIM;   // 33.5M elems
  const size_t DD = (size_t)D_DIM * D_DIM;    // 4.2M elems
  const size_t MiB = 1024 * 1024;

  // d_out (128 MiB) doubles as staging for bf16 x and Wi/Wf/Wg.
  // All of it is dead before the final GEMM writes d_out (stream-ordered).
  char* ob = (char*)d_out;
  bf16_t* xb  = (bf16_t*)(ob);             // 64 MiB
  bf16_t* wib = (bf16_t*)(ob + 64 * MiB);  // 8 MiB
  bf16_t* wfb = (bf16_t*)(ob + 72 * MiB);  // 8 MiB
  bf16_t* wgb = (bf16_t*)(ob + 80 * MiB);  // 8 MiB  (total 88 <= 128 MiB)

  // workspace: 142 MiB total
  char* ws = (char*)d_ws;
  bf16_t* B0  = (bf16_t*)(ws);             // 64 MiB: i -> o -> inner
  bf16_t* B1  = (bf16_t*)(ws + 64 * MiB);  // 64 MiB: f -> g
  bf16_t* wob = (bf16_t*)(ws + 128 * MiB); // 8 MiB  (ws, NOT d_out: final GEMM reads it)
  float*  cA  = (float*)(ws + 136 * MiB);  // 2 MiB
  float*  cB  = (float*)(ws + 138 * MiB);  // 2 MiB
  float*  hin = (float*)(ws + 140 * MiB);  // 2 MiB

  // 1. convert inputs to bf16 (x + 4 weights in 2 dispatches)
  cvt_f32_to_bf16<<<2048, 256, 0, stream>>>(x, xb, (int)(MD / 4));
  CvtBatch cb;
  cb.src[0] = Wi; cb.src[1] = Wf; cb.src[2] = Wg; cb.src[3] = Wo;
  cb.dst[0] = wib; cb.dst[1] = wfb; cb.dst[2] = wgb; cb.dst[3] = wob;
  cvt4_f32_to_bf16<<<dim3(256, 4), 256, 0, stream>>>(cb, (int)(DD / 4));

  // 2. i/f projections -> bf16
  dim3 ggrid(D_DIM / BN, M_ROWS / BM);
  gemm_bt<bf16_t><<<ggrid, 256, 0, stream>>>(xb, wib, B0, M_ROWS, D_DIM, D_DIM);
  gemm_bt<bf16_t><<<ggrid, 256, 0, stream>>>(xb, wfb, B1, M_ROWS, D_DIM, D_DIM);

  // 3. chunked scan (o written in-place over i in B0)
  dim3 sgrid(D_DIM / 256, NCHUNK, N_BATCH);
  scan_phaseA<<<sgrid, 256, 0, stream>>>(B1, B0, cA, cB);
  scan_phaseB<<<32, 256, 0, stream>>>(cA, cB, hin);
  scan_phaseC<<<sgrid, 256, 0, stream>>>(B1, B0, hin, B0);

  // 4. g projection -> bf16 (overwrites f in B1; f consumed by phaseC)
  gemm_bt<bf16_t><<<ggrid, 256, 0, stream>>>(xb, wgb, B1, M_ROWS, D_DIM, D_DIM);

  // 5. rmsnorm + swish gate -> bf16 inner (in-place over o in B0)
  norm_gate<<<M_ROWS, 256, 0, stream>>>(B1, B0, w, B0);

  // 6. output projection -> fp32 d_out (xb/weights in d_out now dead)
  gemm_bt<float><<<ggrid, 256, 0, stream>>>(B0, wob, out, M_ROWS, D_DIM, D_DIM);
}

// Round 5
// 875.315 us; speedup vs baseline: 1.3797x; 1.2966x over previous
//
#include <hip/hip_runtime.h>
#include <hip/hip_bf16.h>
#include <cstdint>
#include <cstddef>

#define D_DIM 2048
#define L_SEQ 4096
#define N_BATCH 4
#define M_ROWS (L_SEQ * N_BATCH)   // 16384
#define NCHUNK 64
#define LCHUNK (L_SEQ / NCHUNK)    // 64

typedef __bf16 bf16_t;
typedef __bf16 bf16x4_t __attribute__((ext_vector_type(4)));
typedef __bf16 bf16x8_t __attribute__((ext_vector_type(8)));
typedef float f32x4_t __attribute__((ext_vector_type(4)));

#define GLD16(SRC, DST) __builtin_amdgcn_global_load_lds(                      \
    (const __attribute__((address_space(1))) void*)(SRC),                      \
    (__attribute__((address_space(3))) void*)(DST), 16, 0, 0)

// ---------------- fp32 -> bf16 convert (vectorized) ----------------
__global__ __launch_bounds__(256) void cvt_f32_to_bf16(const float* __restrict__ in,
                                                       bf16_t* __restrict__ out, int n4) {
  int idx = blockIdx.x * blockDim.x + threadIdx.x;
  int stride = gridDim.x * blockDim.x;
  const float4* in4 = reinterpret_cast<const float4*>(in);
  bf16x4_t* out4 = reinterpret_cast<bf16x4_t*>(out);
  for (int i = idx; i < n4; i += stride) {
    float4 v = in4[i];
    bf16x4_t o;
    o[0] = (bf16_t)v.x; o[1] = (bf16_t)v.y; o[2] = (bf16_t)v.z; o[3] = (bf16_t)v.w;
    out4[i] = o;
  }
}

struct CvtBatch { const float* src[4]; bf16_t* dst[4]; };
__global__ __launch_bounds__(256) void cvt4_f32_to_bf16(CvtBatch cb, int n4) {
  const float4* in4 = reinterpret_cast<const float4*>(cb.src[blockIdx.y]);
  bf16x4_t* out4 = reinterpret_cast<bf16x4_t*>(cb.dst[blockIdx.y]);
  int stride = gridDim.x * blockDim.x;
  for (int i = blockIdx.x * blockDim.x + threadIdx.x; i < n4; i += stride) {
    float4 v = in4[i];
    bf16x4_t o;
    o[0] = (bf16_t)v.x; o[1] = (bf16_t)v.y; o[2] = (bf16_t)v.z; o[3] = (bf16_t)v.w;
    out4[i] = o;
  }
}

// ======= 256x256 8-phase bf16 GEMM: C[M][N] = A[M][K] * Wt[N][K]^T =======
// STATIC 128 KiB LDS (no dynamic-shared launch path).
// Geometry: K-tile 64 = 2 k-halves of 32. LDS layout:
//   buf d (64KB): A.h0 | A.h1 | B.h0 | B.h1, each 16KB = 256 rows x 32 k (64B/row).
// Swizzle (T2): within a row, byte_off ^= ((row>>1)&3)<<4; applied to stage
// SOURCE addr and ds_read addr; gload_lds LDS dest stays linear (rule 21).
// Waits (T4): counted vmcnt(4) at phases 2,4 of each tile; never 0 in main loop.
// Per phase (T3): ds_read frags -> stage 1 half-tile -> [vmcnt] -> s_barrier ->
//   lgkmcnt(0) -> sched_barrier(0) -> setprio(1) -> 16 MFMA -> setprio(0) -> s_barrier.

#define PH(d, kh, ch, DOSTAGE, SMAT, SKH, ST, VM)                               \
  do {                                                                          \
    const char* Ah_ = lds + (((d) << 16) | ((kh) << 14));                       \
    bf16x8_t afr0 = *(const bf16x8_t*)(Ah_ + (aRowBase + ((ch)*4 + 0)*16)*64 + axoff); \
    bf16x8_t afr1 = *(const bf16x8_t*)(Ah_ + (aRowBase + ((ch)*4 + 1)*16)*64 + axoff); \
    bf16x8_t afr2 = *(const bf16x8_t*)(Ah_ + (aRowBase + ((ch)*4 + 2)*16)*64 + axoff); \
    bf16x8_t afr3 = *(const bf16x8_t*)(Ah_ + (aRowBase + ((ch)*4 + 3)*16)*64 + axoff); \
    if ((ch) == 0) {                                                            \
      const char* Bh_ = lds + (((d) << 16) | (1 << 15) | ((kh) << 14));         \
      bfr[0] = *(const bf16x8_t*)(Bh_ + (bRowBase +  0)*64 + axoff);            \
      bfr[1] = *(const bf16x8_t*)(Bh_ + (bRowBase + 16)*64 + axoff);            \
      bfr[2] = *(const bf16x8_t*)(Bh_ + (bRowBase + 32)*64 + axoff);            \
      bfr[3] = *(const bf16x8_t*)(Bh_ + (bRowBase + 48)*64 + axoff);            \
    }                                                                           \
    if (DOSTAGE) {                                                              \
      const char* src_ = ((SMAT) ? bSrc : aSrc) + ((ST)*128 + (SKH)*64);        \
      char* dst_ = lds + ((((d)^1) << 16) | ((SMAT) << 15) | ((SKH) << 14));    \
      GLD16(src_, dst_ + ldsOff0);                                              \
      GLD16(src_ + rowStep, dst_ + ldsOff1);                                    \
    }                                                                           \
    if ((VM) == 4) asm volatile("s_waitcnt vmcnt(4)" ::: "memory");             \
    if ((VM) == 0) asm volatile("s_waitcnt vmcnt(0)" ::: "memory");             \
    __builtin_amdgcn_s_barrier();                                               \
    asm volatile("s_waitcnt lgkmcnt(0)" ::: "memory");                          \
    __builtin_amdgcn_sched_barrier(0);                                          \
    __builtin_amdgcn_s_setprio(1);                                              \
    _Pragma("unroll")                                                           \
    for (int nn = 0; nn < 4; ++nn) {                                            \
      acc[(ch)*4 + 0][nn] = __builtin_amdgcn_mfma_f32_16x16x32_bf16(afr0, bfr[nn], acc[(ch)*4 + 0][nn], 0, 0, 0); \
      acc[(ch)*4 + 1][nn] = __builtin_amdgcn_mfma_f32_16x16x32_bf16(afr1, bfr[nn], acc[(ch)*4 + 1][nn], 0, 0, 0); \
      acc[(ch)*4 + 2][nn] = __builtin_amdgcn_mfma_f32_16x16x32_bf16(afr2, bfr[nn], acc[(ch)*4 + 2][nn], 0, 0, 0); \
      acc[(ch)*4 + 3][nn] = __builtin_amdgcn_mfma_f32_16x16x32_bf16(afr3, bfr[nn], acc[(ch)*4 + 3][nn], 0, 0, 0); \
    }                                                                           \
    __builtin_amdgcn_s_setprio(0);                                              \
    __builtin_amdgcn_s_barrier();                                               \
  } while (0)

template <typename OutT>
__global__ __launch_bounds__(512, 2) void gemm8p(const bf16_t* __restrict__ A,
                                                 const bf16_t* __restrict__ Wt,
                                                 OutT* __restrict__ C) {
  constexpr int K = D_DIM, N = D_DIM;   // 2048; 32 K-tiles of 64
  __shared__ __attribute__((aligned(16))) char lds[131072];
  const int tid = threadIdx.x;
  const int wid = tid >> 6, lane = tid & 63;
  const int wr = wid >> 2, wc = wid & 3;       // 2 x 4 waves, 128x64 each
  const int j = lane & 15, g = lane >> 4;

  // XCD-aware bijective swizzle: nwg = 512, grid (8, 64)
  const int bid = blockIdx.y * 8 + blockIdx.x;
  const int swzb = (bid & 7) * 64 + (bid >> 3);
  const int by = swzb >> 3, bx = swzb & 7;
  const int m0 = by * 256, n0 = bx * 256;

  // staging: thread covers LDS bytes [tid*16) and [(tid+512)*16) of each half.
  // content(row = u>>2, off = ((u&3)<<4) ^ swz(row)), swz(row) = ((row>>1)&3)<<4
  const int srow = tid >> 2;                                    // 0..127 (q0)
  const int soff = ((tid & 3) << 4) ^ (((tid >> 3) & 3) << 4);  // pre-inv-swizzled
  const char* aSrc = (const char*)A + (size_t)(m0 + srow) * (K * 2) + soff;
  const char* bSrc = (const char*)Wt + (size_t)(n0 + srow) * (K * 2) + soff;
  const size_t rowStep = (size_t)128 * K * 2;                   // q1 = +128 rows
  const int ldsOff0 = tid * 16, ldsOff1 = (tid + 512) * 16;

  // fragment read addressing (swizzled): swz(row)=((j>>1)&3)<<4 since row≡j mod 16
  const int axoff = (g << 4) ^ (((j >> 1) & 3) << 4);
  const int aRowBase = wr * 128 + j;
  const int bRowBase = wc * 64 + j;

  f32x4_t acc[8][4] = {};
  bf16x8_t bfr[4];

  // prologue: stage tile 0 (A.h0, B.h0 first, then A.h1, B.h1) -> buf 0
  GLD16(aSrc,            lds + ldsOff0);
  GLD16(aSrc + rowStep,  lds + ldsOff1);
  GLD16(bSrc,            lds + 32768 + ldsOff0);
  GLD16(bSrc + rowStep,  lds + 32768 + ldsOff1);
  GLD16(aSrc + 64,           lds + 16384 + ldsOff0);
  GLD16(aSrc + 64 + rowStep, lds + 16384 + ldsOff1);
  GLD16(bSrc + 64,           lds + 49152 + ldsOff0);
  GLD16(bSrc + 64 + rowStep, lds + 49152 + ldsOff1);
  asm volatile("s_waitcnt vmcnt(4)" ::: "memory");   // A.h0,B.h0 landed
  __builtin_amdgcn_s_barrier();

  // main loop: tiles 0..30 with 1-tile-ahead staging
  for (int t = 0; t < 31; ++t) {
    const int d = t & 1;
    PH(d, 0, 0, 1, 0, 0, t + 1, -1);   // stage A.h0(t+1)
    PH(d, 0, 1, 1, 1, 0, t + 1, 4);    // stage B.h0(t+1), vmcnt(4)
    PH(d, 1, 0, 1, 0, 1, t + 1, -1);   // stage A.h1(t+1)
    PH(d, 1, 1, 1, 1, 1, t + 1, 4);    // stage B.h1(t+1), vmcnt(4)
  }
  // last tile (31, buf 1): no staging; drain remaining halves at ph2
  PH(1, 0, 0, 0, 0, 0, 0, -1);
  PH(1, 0, 1, 0, 0, 0, 0, 0);          // vmcnt(0): A.h1,B.h1(31) landed
  PH(1, 1, 0, 0, 0, 0, 0, -1);
  PH(1, 1, 1, 0, 0, 0, 0, -1);

  // epilogue: C/D layout col=lane&15, row=4*(lane>>4)+reg [m89]
  const int crow = (lane >> 4) * 4, ccol = lane & 15;
  const int gmBase = m0 + wr * 128 + crow;
  const int gnBase = n0 + wc * 64 + ccol;
  #pragma unroll
  for (int mr = 0; mr < 8; ++mr) {
    #pragma unroll
    for (int r = 0; r < 4; ++r) {
      OutT* Cp = C + (size_t)(gmBase + mr * 16 + r) * N + gnBase;
      #pragma unroll
      for (int nn = 0; nn < 4; ++nn) Cp[nn * 16] = (OutT)acc[mr][nn][r];
    }
  }
}

// ---------------- chunked scan: h_t = gate_t * h_{t-1} + iin_t ----------------
__device__ __forceinline__ float sigmoidf_fast(float x) {
  return 1.0f / (1.0f + __expf(-x));
}

__global__ __launch_bounds__(256) void scan_phaseA(const bf16_t* __restrict__ f,
                                                   const bf16_t* __restrict__ i_,
                                                   float* __restrict__ cA,
                                                   float* __restrict__ cB) {
  const int d = blockIdx.x * 256 + threadIdx.x;
  const int c = blockIdx.y;
  const int b = blockIdx.z;
  size_t base = ((size_t)b * L_SEQ + (size_t)c * LCHUNK) * D_DIM + d;
  float aprod = 1.0f, h = 0.0f;
  for (int t = 0; t < LCHUNK; ++t) {
    float fv = (float)f[base + (size_t)t * D_DIM];
    float iv = (float)i_[base + (size_t)t * D_DIM];
    float gate = sigmoidf_fast(fv);
    float iin = iv * sigmoidf_fast(iv) * (1.0f - gate);
    aprod *= gate;
    h = gate * h + iin;
  }
  size_t p = ((size_t)b * NCHUNK + c) * D_DIM + d;
  cA[p] = aprod;
  cB[p] = h;
}

__global__ __launch_bounds__(256) void scan_phaseB(const float* __restrict__ cA,
                                                   const float* __restrict__ cB,
                                                   float* __restrict__ hin) {
  int idx = blockIdx.x * blockDim.x + threadIdx.x;  // over B*D = 8192
  int b = idx >> 11;
  int d = idx & (D_DIM - 1);
  float h = 0.0f;
  for (int c = 0; c < NCHUNK; ++c) {
    size_t p = ((size_t)b * NCHUNK + c) * D_DIM + d;
    hin[p] = h;
    h = cA[p] * h + cB[p];
  }
}

__global__ __launch_bounds__(256) void scan_phaseC(const bf16_t* __restrict__ f,
                                                   const bf16_t* __restrict__ i_,
                                                   const float* __restrict__ hin,
                                                   bf16_t* __restrict__ o) {
  const int d = blockIdx.x * 256 + threadIdx.x;
  const int c = blockIdx.y;
  const int b = blockIdx.z;
  size_t base = ((size_t)b * L_SEQ + (size_t)c * LCHUNK) * D_DIM + d;
  float h = hin[((size_t)b * NCHUNK + c) * D_DIM + d];
  for (int t = 0; t < LCHUNK; ++t) {
    float fv = (float)f[base + (size_t)t * D_DIM];
    float iv = (float)i_[base + (size_t)t * D_DIM];  // o aliases i_ — read before write
    float gate = sigmoidf_fast(fv);
    float iin = iv * sigmoidf_fast(iv) * (1.0f - gate);
    h = gate * h + iin;
    o[base + (size_t)t * D_DIM] = (bf16_t)h;
  }
}

// ---------------- RMSNorm(g)*w * swish(o) -> bf16 (inner may alias o) ----------------
__global__ __launch_bounds__(256) void norm_gate(const bf16_t* __restrict__ g,
                                                 const bf16_t* __restrict__ o,
                                                 const float* __restrict__ w,
                                                 bf16_t* __restrict__ inner) {
  const int row = blockIdx.x;
  const int tid = threadIdx.x;
  const bf16x8_t* g8 = reinterpret_cast<const bf16x8_t*>(g + (size_t)row * D_DIM);
  const bf16x8_t* o8 = reinterpret_cast<const bf16x8_t*>(o + (size_t)row * D_DIM);
  const float4* w4 = reinterpret_cast<const float4*>(w);
  bf16x8_t gv = g8[tid];
  float gf[8];
  float ss = 0.0f;
  #pragma unroll
  for (int jj = 0; jj < 8; ++jj) { gf[jj] = (float)gv[jj]; ss += gf[jj] * gf[jj]; }
  #pragma unroll
  for (int off = 32; off > 0; off >>= 1) ss += __shfl_down(ss, off, 64);
  __shared__ float red[4];
  if ((tid & 63) == 0) red[tid >> 6] = ss;
  __syncthreads();
  float tot = red[0] + red[1] + red[2] + red[3];
  float rms = rsqrtf(tot * (1.0f / D_DIM) + 1e-5f);

  bf16x8_t ov = o8[tid];               // read BEFORE writing inner (may alias)
  float4 wa = w4[tid * 2], wb = w4[tid * 2 + 1];
  float wf[8] = {wa.x, wa.y, wa.z, wa.w, wb.x, wb.y, wb.z, wb.w};
  bf16x8_t r;
  #pragma unroll
  for (int jj = 0; jj < 8; ++jj) {
    float of = (float)ov[jj];
    r[jj] = (bf16_t)(gf[jj] * rms * wf[jj] * (of * sigmoidf_fast(of)));
  }
  bf16x8_t* inn8 = reinterpret_cast<bf16x8_t*>(inner + (size_t)row * D_DIM);
  inn8[tid] = r;
}

// ---------------- launch ----------------
extern "C" void kernel_launch(void* const* d_in, const int* in_sizes, int n_in,
                              void* d_out, int out_size, void* d_ws, size_t ws_size,
                              hipStream_t stream) {
  const float* x  = (const float*)d_in[0];
  const float* Wi = (const float*)d_in[1];
  const float* Wf = (const float*)d_in[2];
  const float* Wg = (const float*)d_in[3];
  const float* w  = (const float*)d_in[4];
  const float* Wo = (const float*)d_in[5];
  float* out = (float*)d_out;

  const size_t MD = (size_t)M_ROWS * D_DIM;
  const size_t DD = (size_t)D_DIM * D_DIM;
  const size_t MiB = 1024 * 1024;

  // d_out (128 MiB) stages bf16 x + Wi/Wf/Wg; all dead before final GEMM writes.
  char* ob = (char*)d_out;
  bf16_t* xb  = (bf16_t*)(ob);             // 64 MiB
  bf16_t* wib = (bf16_t*)(ob + 64 * MiB);  // 8 MiB
  bf16_t* wfb = (bf16_t*)(ob + 72 * MiB);  // 8 MiB
  bf16_t* wgb = (bf16_t*)(ob + 80 * MiB);  // 8 MiB

  // workspace: 142 MiB total
  char* ws = (char*)d_ws;
  bf16_t* B0  = (bf16_t*)(ws);             // 64 MiB: i -> o -> inner
  bf16_t* B1  = (bf16_t*)(ws + 64 * MiB);  // 64 MiB: f -> g
  bf16_t* wob = (bf16_t*)(ws + 128 * MiB); // 8 MiB
  float*  cA  = (float*)(ws + 136 * MiB);  // 2 MiB
  float*  cB  = (float*)(ws + 138 * MiB);  // 2 MiB
  float*  hin = (float*)(ws + 140 * MiB);  // 2 MiB

  // 1. convert inputs to bf16
  cvt_f32_to_bf16<<<2048, 256, 0, stream>>>(x, xb, (int)(MD / 4));
  CvtBatch cb;
  cb.src[0] = Wi; cb.src[1] = Wf; cb.src[2] = Wg; cb.src[3] = Wo;
  cb.dst[0] = wib; cb.dst[1] = wfb; cb.dst[2] = wgb; cb.dst[3] = wob;
  cvt4_f32_to_bf16<<<dim3(256, 4), 256, 0, stream>>>(cb, (int)(DD / 4));

  // 2. i/f projections -> bf16 (256^2 8-phase, static 128 KiB LDS)
  dim3 ggrid(D_DIM / 256, M_ROWS / 256);   // (8, 64)
  gemm8p<bf16_t><<<ggrid, 512, 0, stream>>>(xb, wib, B0);
  gemm8p<bf16_t><<<ggrid, 512, 0, stream>>>(xb, wfb, B1);

  // 3. chunked scan (o written in-place over i in B0)
  dim3 sgrid(D_DIM / 256, NCHUNK, N_BATCH);
  scan_phaseA<<<sgrid, 256, 0, stream>>>(B1, B0, cA, cB);
  scan_phaseB<<<32, 256, 0, stream>>>(cA, cB, hin);
  scan_phaseC<<<sgrid, 256, 0, stream>>>(B1, B0, hin, B0);

  // 4. g projection -> bf16 (overwrites f in B1; f consumed by phaseC)
  gemm8p<bf16_t><<<ggrid, 512, 0, stream>>>(xb, wgb, B1);

  // 5. rmsnorm + swish gate -> bf16 inner (in-place over o in B0)
  norm_gate<<<M_ROWS, 256, 0, stream>>>(B1, B0, w, B0);

  // 6. output projection -> fp32 d_out
  gemm8p<float><<<ggrid, 512, 0, stream>>>(B0, wob, out);
}